// Round 1
// baseline (271.225 us; speedup 1.0000x reference)
//
#include <hip/hip_runtime.h>

// XOR chain = inclusive prefix-XOR along axis 0 of [S=4096, B=8192] int32.
// Round 15: persistent multi-round blocks. R14 (81 us kernel) was half-duplex:
// 512 all-resident single-chunk blocks load in lockstep, then store in
// lockstep => read and write phases serialize (2x the 41 us roofline).
// Now: OUTER=8 rows/chunk => 4096 tickets, 1024 persistent blocks (4/CU,
// 16 waves/CU) loop over ~4 tickets each. After round 1 blocks desync, so
// loads of chunk r+1 overlap stores of chunk r => HBM full-duplex, and 2x
// occupancy hides latency within each phase. Lookback fast-path (inc of o-1)
// almost always hits since the predecessor was ticketed 8 earlier.
// Ticket + agg/inc tables remain poison-self-initializing (R12-proven).
// Deadlock-free: a block spins only on strictly lower tickets.

#define S 4096
#define B4 2048              // v4u column-groups per row
#define TPB 256
#define NCT 8                // coltiles = B4/TPB
#define OUTER 8              // rows per chunk
#define NOUT (S / OUTER)     // 512 chunk-rows
#define NTICK (NOUT * NCT)   // 4096 tickets
#define NBLK 1024            // persistent blocks, 4/CU
#define NWORDS (NOUT * B4)   // 1M dwords = 4 MB per table
#define POISON 0xAAAAAAAAu

typedef unsigned int v4u __attribute__((ext_vector_type(4)));

__device__ __forceinline__ bool valid(unsigned w) {
    return (w & 0x300u) == 0x100u;   // 0xAAAAAAAA poison and 0 both fail
}

__global__ __launch_bounds__(TPB, 4) void xor_persist(
        const v4u* __restrict__ in, v4u* __restrict__ out,
        unsigned* __restrict__ ctl) {
    unsigned* agg = ctl + 64;
    unsigned* inc = agg + NWORDS;

    __shared__ unsigned sh_t;
    const int tid = threadIdx.x;

    for (;;) {
        if (tid == 0) sh_t = atomicAdd(&ctl[0], 1u) - POISON;  // self-init ticket
        __syncthreads();
        const unsigned t = sh_t;
        __syncthreads();               // all lanes read sh_t before next write
        if (t >= NTICK) return;

        const int ct       = (int)(t & (NCT - 1u));
        const unsigned o   = t >> 3;   // chunk-row; ticket order => preds started
        const int colg     = ct * TPB + tid;

        // ---- Load 8 rows, pack nibble-per-row into one u32 ----
        const v4u* p = in + (size_t)o * OUTER * B4 + colg;
        v4u v[OUTER];
#pragma unroll
        for (int j = 0; j < OUTER; ++j) v[j] = p[(size_t)j * B4];

        unsigned q = 0u;
#pragma unroll
        for (int j = 0; j < OUTER; ++j) {
            unsigned n = (v[j].x & 1u) | ((v[j].y & 1u) << 1) |
                         ((v[j].z & 1u) << 2) | ((v[j].w & 1u) << 3);
            q |= n << (4 * j);
        }

        // ---- Publish aggregate nibble (XOR of the 8 row-nibbles) ----
        unsigned a = q;
        a ^= a >> 16; a ^= a >> 8; a ^= a >> 4;
        const unsigned myagg = a & 0xFu;
        __hip_atomic_store(&agg[(size_t)o * B4 + colg], 0x100u | myagg,
                           __ATOMIC_RELAXED, __HIP_MEMORY_SCOPE_AGENT);

        // ---- Lookback: inc fast path + 16-wide batched agg polls ----
        unsigned ex = 0u;
        int k = (int)o - 1;
        while (k >= 0) {
            unsigned iw = __hip_atomic_load(&inc[(size_t)k * B4 + colg],
                                            __ATOMIC_RELAXED,
                                            __HIP_MEMORY_SCOPE_AGENT);
            if (valid(iw)) { ex ^= (iw & 0xFu); break; }
            int n = (k + 1 < 16) ? (k + 1) : 16;
            unsigned aw[16];
            for (int j = 0; j < n; ++j)
                aw[j] = __hip_atomic_load(&agg[(size_t)(k - j) * B4 + colg],
                                          __ATOMIC_RELAXED,
                                          __HIP_MEMORY_SCOPE_AGENT);
            int consumed = 0;
            for (int j = 0; j < n; ++j) {
                if (valid(aw[j])) { ex ^= (aw[j] & 0xFu); ++consumed; }
                else break;
            }
            k -= consumed;
            if (consumed == 0) __builtin_amdgcn_s_sleep(1);
        }
        __hip_atomic_store(&inc[(size_t)o * B4 + colg], 0x100u | (ex ^ myagg),
                           __ATOMIC_RELAXED, __HIP_MEMORY_SCOPE_AGENT);

        // ---- Scan (3 shift-XOR steps), seed, unpack, NT store ----
        unsigned x = q;
        x ^= x << 4; x ^= x << 8; x ^= x << 16;          // in-chunk prefix-XOR
        const unsigned f = x ^ (ex * 0x11111111u);       // replicate seed nibble

        v4u* qo = out + (size_t)o * OUTER * B4 + colg;
#pragma unroll
        for (int j = 0; j < OUTER; ++j) {
            const unsigned n = (f >> (4 * j)) & 0xFu;
            v4u ov = (v4u){n & 1u, (n >> 1) & 1u, (n >> 2) & 1u, (n >> 3) & 1u};
            __builtin_nontemporal_store(ov, &qo[(size_t)j * B4]);
        }
    }
}

extern "C" void kernel_launch(void* const* d_in, const int* in_sizes, int n_in,
                              void* d_out, int out_size, void* d_ws, size_t ws_size,
                              hipStream_t stream) {
    const v4u* in = (const v4u*)d_in[0];
    v4u* out = (v4u*)d_out;
    unsigned* ctl = (unsigned*)d_ws;  // [0..63] ctl, then agg (4 MB) + inc (4 MB)

    xor_persist<<<NBLK, TPB, 0, stream>>>(in, out, ctl);
}

// Round 2
// 241.555 us; speedup vs baseline: 1.1228x; 1.1228x over previous
//
#include <hip/hip_runtime.h>

// XOR chain = inclusive prefix-XOR along axis 0 of [S=4096, B=8192] int32.
// Round 16: fix load MLP. R14/R15 both report VGPR_Count=28, proving the
// compiler serialized the staging loads to load->use->use (only ~2-3 loads in
// flight per wave => load phase latency-bound at ~half of read peak; that is
// R14's missing 2x, and R15's extra control ops made it worse, not better).
// Fix: per 16-row batch, issue all 16 global loads, then a
// sched_barrier(0) fence, then the pack VALU -- the register allocator must
// keep 16 results live (64 VGPRs) => 16 loads in flight per wave.
// Structure: single-shot blocks (R14-proven), OUTER=32 rows/chunk,
// 1024 blocks = 4/CU all resident (2x waves of R14, only 2x control ops,
// 1 MB per lookback table). Ticket + agg/inc tables poison-self-init
// (R12-proven). Deadlock-free: blocks poll only strictly lower tickets.

#define S 4096
#define B4 2048              // v4u column-groups per row
#define TPB 256
#define NCT 8                // coltiles = B4/TPB
#define OUTER 32             // rows per chunk
#define NOUT (S / OUTER)     // 128 chunk-rows
#define NBLK (NOUT * NCT)    // 1024 blocks, 4/CU, all resident
#define NWORDS (NOUT * B4)   // 256K dwords = 1 MB per table
#define POISON 0xAAAAAAAAu

typedef unsigned int v4u __attribute__((ext_vector_type(4)));
typedef unsigned long long u64;

__device__ __forceinline__ bool valid(unsigned w) {
    return (w & 0x300u) == 0x100u;   // 0xAAAAAAAA poison and 0 both fail
}
__device__ __forceinline__ u64 repl(unsigned nib) {   // nibble -> 16 copies
    u64 m = nib;
    m |= m << 4; m |= m << 8; m |= m << 16; m |= m << 32;
    return m;
}

__global__ __launch_bounds__(TPB, 4) void xor_mlp(
        const v4u* __restrict__ in, v4u* __restrict__ out,
        unsigned* __restrict__ ctl) {
    unsigned* agg = ctl + 64;
    unsigned* inc = agg + NWORDS;

    __shared__ unsigned sh_t;
    const int tid = threadIdx.x;
    if (tid == 0) sh_t = atomicAdd(&ctl[0], 1u) - POISON;  // self-init ticket
    __syncthreads();
    const unsigned t = sh_t;
    const int ct   = (int)(t & (NCT - 1));
    const int o    = (int)(t >> 3);    // ticket order => predecessors started
    const int colg = ct * TPB + tid;

    const v4u* p = in + (size_t)o * OUTER * B4 + colg;

    // ---- Load 32 rows in two 16-deep fenced batches, pack nibble/row ----
    u64 q[2] = {0ull, 0ull};
#pragma unroll
    for (int b = 0; b < 2; ++b) {
        v4u v[16];
#pragma unroll
        for (int j = 0; j < 16; ++j) v[j] = p[(size_t)(b * 16 + j) * B4];
        // Pin schedule: all 16 loads issued before any pack VALU => 16 loads
        // in flight per wave (the whole point of this round).
        __builtin_amdgcn_sched_barrier(0);
#pragma unroll
        for (int j = 0; j < 16; ++j) {
            unsigned n = (v[j].x & 1u) | ((v[j].y & 1u) << 1) |
                         ((v[j].z & 1u) << 2) | ((v[j].w & 1u) << 3);
            q[b] ^= (u64)n << (4 * j);
        }
    }

    // ---- Publish aggregate nibble (XOR of all 32 row-nibbles) ----
    u64 tt = q[0] ^ q[1];
    tt ^= tt >> 32; tt ^= tt >> 16; tt ^= tt >> 8; tt ^= tt >> 4;
    const unsigned myagg = (unsigned)tt & 0xFu;
    __hip_atomic_store(&agg[(size_t)o * B4 + colg], 0x100u | myagg,
                       __ATOMIC_RELAXED, __HIP_MEMORY_SCOPE_AGENT);

    // ---- Lookback: inc fast path + 16-wide batched agg polls ----
    unsigned ex = 0u;
    int k = o - 1;
    while (k >= 0) {
        unsigned iw = __hip_atomic_load(&inc[(size_t)k * B4 + colg],
                                        __ATOMIC_RELAXED,
                                        __HIP_MEMORY_SCOPE_AGENT);
        if (valid(iw)) { ex ^= (iw & 0xFu); break; }
        int n = (k + 1 < 16) ? (k + 1) : 16;
        unsigned a[16];
        for (int j = 0; j < n; ++j)
            a[j] = __hip_atomic_load(&agg[(size_t)(k - j) * B4 + colg],
                                     __ATOMIC_RELAXED,
                                     __HIP_MEMORY_SCOPE_AGENT);
        int consumed = 0;
        for (int j = 0; j < n; ++j) {
            if (valid(a[j])) { ex ^= (a[j] & 0xFu); ++consumed; }
            else break;
        }
        k -= consumed;
        if (consumed == 0) __builtin_amdgcn_s_sleep(1);
    }
    __hip_atomic_store(&inc[(size_t)o * B4 + colg], 0x100u | (ex ^ myagg),
                       __ATOMIC_RELAXED, __HIP_MEMORY_SCOPE_AGENT);

    // ---- Scan (4 shift-XOR steps per u64), seed, unpack, NT store ----
    unsigned carry = ex;
    v4u* qo = out + (size_t)o * OUTER * B4 + colg;
#pragma unroll
    for (int kk = 0; kk < 2; ++kk) {
        u64 x = q[kk];
        x ^= x << 4; x ^= x << 8; x ^= x << 16; x ^= x << 32;  // prefix-XOR
        const u64 f = x ^ repl(carry);
        carry ^= (unsigned)(x >> 60) & 0xFu;
#pragma unroll
        for (int j = 0; j < 16; ++j) {
            const unsigned n = (unsigned)(f >> (4 * j)) & 0xFu;
            v4u ov = (v4u){n & 1u, (n >> 1) & 1u, (n >> 2) & 1u, (n >> 3) & 1u};
            __builtin_nontemporal_store(ov, &qo[(size_t)(kk * 16 + j) * B4]);
        }
    }
}

extern "C" void kernel_launch(void* const* d_in, const int* in_sizes, int n_in,
                              void* d_out, int out_size, void* d_ws, size_t ws_size,
                              hipStream_t stream) {
    const v4u* in = (const v4u*)d_in[0];
    v4u* out = (v4u*)d_out;
    unsigned* ctl = (unsigned*)d_ws;  // [0..63] ctl, then agg (1 MB) + inc (1 MB)

    xor_mlp<<<NBLK, TPB, 0, stream>>>(in, out, ctl);
}

// Round 3
// 237.224 us; speedup vs baseline: 1.1433x; 1.0183x over previous
//
#include <hip/hip_runtime.h>
#include <stdint.h>

// XOR chain = inclusive prefix-XOR along axis 0 of [S=4096, B=8192] int32.
// Round 17: (a) drop the ticket -- all-resident grid (256 blocks, 1/CU) makes
// blockIdx-order lookback deadlock-free, saving ~8us of serialized
// same-address atomics (R14->R16 delta: ~15ns/atomic). (b) force read MLP in
// hardware: VGPR=28/36 across R14/R16 proves hipcc never keeps >4-5 register
// loads in flight; use global_load_lds (DMA->LDS, vmcnt-tracked, no VGPRs).
// Each of the 16 waves/CU owns private LDS slabs (no __syncthreads => no
// compiler vmcnt(0) drain), 4-row double-buffered stages with hand-counted
// s_waitcnt vmcnt(4): steady 8KB in flight/wave x 16 waves = 128KB/CU >>
// ~18KB Little's-law need. Compute core (nibble pack, u64 shift-XOR scan,
// 16-wide batched agg lookback, poison-self-init tables, NT stores) is
// R12/R14-proven, unchanged; table geometry identical to R14 (512KB each).

#define S 4096
#define B4 2048               // v4u column-groups per row
#define TPB 512
#define NCT (B4 / TPB)        // 4 coltiles
#define OUTER 64              // rows per chunk
#define NOUT (S / OUTER)      // 64 chunk-rows
#define NBLK (NOUT * NCT)     // 256 blocks, 1/CU, all resident
#define NWORDS (NOUT * B4)    // 128K dwords = 512 KB per table
#define POISON 0xAAAAAAAAu
#define STG 4                 // rows per stage
#define NSTG (OUTER / STG)    // 16 stages

typedef unsigned int v4u __attribute__((ext_vector_type(4)));
typedef unsigned long long u64;
typedef const __attribute__((address_space(1))) v4u* gp1_t;
typedef __attribute__((address_space(3))) v4u* lp3_t;

__device__ __forceinline__ bool valid(unsigned w) {
    return (w & 0x300u) == 0x100u;   // 0xAAAAAAAA poison and 0 both fail
}
__device__ __forceinline__ u64 repl(unsigned nib) {   // nibble -> 16 copies
    u64 m = nib;
    m |= m << 4; m |= m << 8; m |= m << 16; m |= m << 32;
    return m;
}

__global__ __launch_bounds__(TPB) void xor_ldsdma(
        const v4u* __restrict__ in, v4u* __restrict__ out,
        unsigned* __restrict__ ctl) {
    unsigned* agg = ctl + 64;
    unsigned* inc = agg + NWORDS;

    __shared__ v4u sh[2][STG][TPB];   // 64 KB, per-wave-private slabs

    const int tid   = (int)threadIdx.x;
    const int bid   = (int)blockIdx.x;
    const int ct    = bid & (NCT - 1);
    const int o     = bid >> 2;              // NCT = 4
    const int colg  = ct * TPB + tid;
    const int wbase = tid & ~63;             // wave-uniform lane base

    const v4u* p = in + (size_t)o * OUTER * B4 + colg;

    // ---- DMA-staged load of 64 rows: 16 stages x 4 rows, double-buffered.
    // global src is per-lane (colg), LDS dst is wave-uniform base; HW writes
    // lane l at base + 16*l => sh[buf][j][tid] holds row's v4u for this lane.
    auto STAGE = [&](int srow, int buf) {
#pragma unroll
        for (int j = 0; j < STG; ++j)
            __builtin_amdgcn_global_load_lds(
                (gp1_t)(const void*)(p + (size_t)(srow + j) * B4),
                (lp3_t)(void*)&sh[buf][j][wbase], 16, 0, 0);
    };

    u64 q[4] = {0ull, 0ull, 0ull, 0ull};
    STAGE(0, 0);
    STAGE(STG, 1);
#pragma unroll
    for (int s = 0; s < NSTG; ++s) {
        if (s < NSTG - 1) asm volatile("s_waitcnt vmcnt(4)" ::: "memory");
        else              asm volatile("s_waitcnt vmcnt(0)" ::: "memory");
        const int buf = s & 1;
#pragma unroll
        for (int j = 0; j < STG; ++j) {
            v4u v = sh[buf][j][tid];
            unsigned n = (v.x & 1u) | ((v.y & 1u) << 1) |
                         ((v.z & 1u) << 2) | ((v.w & 1u) << 3);
            const int r = s * STG + j;
            q[r >> 4] ^= (u64)n << (4 * (r & 15));
        }
        // ds_reads fully retired before the DMA can overwrite this buffer
        asm volatile("s_waitcnt lgkmcnt(0)" ::: "memory");
        if (s + 2 < NSTG) STAGE((s + 2) * STG, buf);
    }

    // ---- Publish aggregate nibble (XOR of all 64 row-nibbles) ----
    u64 tt = q[0] ^ q[1] ^ q[2] ^ q[3];
    tt ^= tt >> 32; tt ^= tt >> 16; tt ^= tt >> 8; tt ^= tt >> 4;
    const unsigned myagg = (unsigned)tt & 0xFu;
    __hip_atomic_store(&agg[(size_t)o * B4 + colg], 0x100u | myagg,
                       __ATOMIC_RELAXED, __HIP_MEMORY_SCOPE_AGENT);

    // ---- Lookback: inc fast path + 16-wide batched agg polls ----
    unsigned ex = 0u;
    int k = o - 1;
    while (k >= 0) {
        unsigned iw = __hip_atomic_load(&inc[(size_t)k * B4 + colg],
                                        __ATOMIC_RELAXED,
                                        __HIP_MEMORY_SCOPE_AGENT);
        if (valid(iw)) { ex ^= (iw & 0xFu); break; }
        int n = (k + 1 < 16) ? (k + 1) : 16;
        unsigned a[16];
        for (int j = 0; j < n; ++j)
            a[j] = __hip_atomic_load(&agg[(size_t)(k - j) * B4 + colg],
                                     __ATOMIC_RELAXED,
                                     __HIP_MEMORY_SCOPE_AGENT);
        int consumed = 0;
        for (int j = 0; j < n; ++j) {
            if (valid(a[j])) { ex ^= (a[j] & 0xFu); ++consumed; }
            else break;
        }
        k -= consumed;
        if (consumed == 0) __builtin_amdgcn_s_sleep(1);
    }
    __hip_atomic_store(&inc[(size_t)o * B4 + colg], 0x100u | (ex ^ myagg),
                       __ATOMIC_RELAXED, __HIP_MEMORY_SCOPE_AGENT);

    // ---- Scan (4 shift-XOR steps per u64), seed, unpack, NT store ----
    unsigned carry = ex;
    v4u* qo = out + (size_t)o * OUTER * B4 + colg;
#pragma unroll
    for (int kk = 0; kk < 4; ++kk) {
        u64 x = q[kk];
        x ^= x << 4; x ^= x << 8; x ^= x << 16; x ^= x << 32;  // prefix-XOR
        const u64 f = x ^ repl(carry);
        carry ^= (unsigned)(x >> 60) & 0xFu;
#pragma unroll
        for (int j = 0; j < 16; ++j) {
            const unsigned n = (unsigned)(f >> (4 * j)) & 0xFu;
            v4u ov = (v4u){n & 1u, (n >> 1) & 1u, (n >> 2) & 1u, (n >> 3) & 1u};
            __builtin_nontemporal_store(ov, &qo[(size_t)(kk * 16 + j) * B4]);
        }
    }
}

extern "C" void kernel_launch(void* const* d_in, const int* in_sizes, int n_in,
                              void* d_out, int out_size, void* d_ws, size_t ws_size,
                              hipStream_t stream) {
    const v4u* in = (const v4u*)d_in[0];
    v4u* out = (v4u*)d_out;
    unsigned* ctl = (unsigned*)d_ws;  // [0..63] ctl, then agg + inc (512 KB each)

    xor_ldsdma<<<NBLK, TPB, 0, stream>>>(in, out, ctl);
}